// Round 1
// baseline (610.694 us; speedup 1.0000x reference)
//
#include <hip/hip_runtime.h>
#include <hip/hip_bf16.h>
#include <cstdint>
#include <cstddef>

#define NH 16
#define HD 64
#define SS 2048
#define DM 1024
#define MTOT 4096   // B*S

typedef __attribute__((ext_vector_type(8))) short short8;
typedef __attribute__((ext_vector_type(4))) float float4v;
typedef __attribute__((ext_vector_type(4))) unsigned short ushort4v;

__device__ __forceinline__ unsigned short f2bf(float f){
  unsigned int u = __builtin_bit_cast(unsigned int, f);
  u += 0x7FFFu + ((u >> 16) & 1u);   // RNE; inputs finite
  return (unsigned short)(u >> 16);
}

__device__ __forceinline__ void gload16(const void* g, void* l){
  __builtin_amdgcn_global_load_lds((const __attribute__((address_space(1))) void*)g,
                                   (__attribute__((address_space(3))) void*)l, 16, 0, 0);
}

// ---------- f32 -> bf16 bulk convert ----------
__global__ __launch_bounds__(256) void cvt_kernel(const float* __restrict__ src,
                                                  unsigned short* __restrict__ dst, int n){
  for (int i = (blockIdx.x*blockDim.x + threadIdx.x)*4; i < n; i += gridDim.x*blockDim.x*4){
    float4v v = *reinterpret_cast<const float4v*>(src + i);
    ushort4v o;
    o.x = f2bf(v.x); o.y = f2bf(v.y); o.z = f2bf(v.z); o.w = f2bf(v.w);
    *reinterpret_cast<ushort4v*>(dst + i) = o;
  }
}

// ---------- GEMM: out = A[M][K] @ Bw[N][K]^T + bias ----------
// MODE 0: bf16 out, head-split [B,H,S,64]
// MODE 1: bf16 out, V-transposed [B,H,64,S]
// MODE 2: f32 out, row-major, * oscale
template<int MODE>
__global__ __launch_bounds__(256) void gemm_bt(const unsigned short* __restrict__ A,
                                               const unsigned short* __restrict__ Bw,
                                               const float* __restrict__ bias,
                                               void* __restrict__ outp,
                                               int M, int N, int K,
                                               const float* __restrict__ oscale_p){
  __shared__ unsigned short Alds[128*32];
  __shared__ unsigned short Blds[128*32];
  const int t = threadIdx.x;
  const int l = t & 63;
  const int w = t >> 6;
  const int m0 = blockIdx.y * 128, n0 = blockIdx.x * 128;
  const int wm = (w & 1)*64, wn = (w >> 1)*64;
  const int srow = t >> 2;          // staging row
  const int scol = (t & 3)*8;       // staging col (bf16 elems)
  const int lr = l & 15, lg = l >> 4;
  float4v acc[4][4] = {};
  for (int k0 = 0; k0 < K; k0 += 32){
    __syncthreads();                 // prior reads done before overwrite
    gload16(A  + (size_t)(m0 + srow     )*K + k0 + scol, Alds + t*8);
    gload16(A  + (size_t)(m0 + srow + 64)*K + k0 + scol, Alds + 2048 + t*8);
    gload16(Bw + (size_t)(n0 + srow     )*K + k0 + scol, Blds + t*8);
    gload16(Bw + (size_t)(n0 + srow + 64)*K + k0 + scol, Blds + 2048 + t*8);
    asm volatile("s_waitcnt vmcnt(0)" ::: "memory");
    __syncthreads();
    short8 afrag[4], bfrag[4];
    #pragma unroll
    for (int mb = 0; mb < 4; ++mb)
      afrag[mb] = *reinterpret_cast<const short8*>(Alds + (wm + mb*16 + lr)*32 + lg*8);
    #pragma unroll
    for (int nb = 0; nb < 4; ++nb)
      bfrag[nb] = *reinterpret_cast<const short8*>(Blds + (wn + nb*16 + lr)*32 + lg*8);
    #pragma unroll
    for (int mb = 0; mb < 4; ++mb)
      #pragma unroll
      for (int nb = 0; nb < 4; ++nb)
        acc[mb][nb] = __builtin_amdgcn_mfma_f32_16x16x32_bf16(afrag[mb], bfrag[nb], acc[mb][nb], 0, 0, 0);
  }
  const float osc = (MODE == 2) ? oscale_p[0] : 1.0f;
  #pragma unroll
  for (int mb = 0; mb < 4; ++mb){
    #pragma unroll
    for (int nb = 0; nb < 4; ++nb){
      const int gn = n0 + wn + nb*16 + lr;
      const float biasv = bias[gn];
      #pragma unroll
      for (int r = 0; r < 4; ++r){
        const int gm = m0 + wm + mb*16 + lg*4 + r;
        float v = acc[mb][nb][r] + biasv;
        if (MODE == 2){
          reinterpret_cast<float*>(outp)[(size_t)gm*N + gn] = v * osc;
        } else {
          const int b_ = gm >> 11, s_ = gm & 2047, h_ = gn >> 6, d_ = gn & 63;
          unsigned short* o = reinterpret_cast<unsigned short*>(outp);
          if (MODE == 0)
            o[((size_t)(b_*NH + h_)*SS + s_)*HD + d_] = f2bf(v);
          else
            o[((size_t)(b_*NH + h_)*HD + d_)*SS + s_] = f2bf(v);
        }
      }
    }
  }
}

// ---------- fused attention: scores -> softmax -> weights out + PV ----------
__global__ __launch_bounds__(512) void attn_kernel(
    const unsigned short* __restrict__ Qh,   // [B*H][S][64] bf16
    const unsigned short* __restrict__ Kh,   // [B*H][S][64] bf16
    const unsigned short* __restrict__ Vt,   // [B*H][64][S] bf16
    unsigned short* __restrict__ AO,         // [B][S][1024] bf16
    float* __restrict__ attnW,               // [B*H][S][S] f32
    const float* __restrict__ phase,         // [B]
    const float* __restrict__ pc,            // [16]
    const float* __restrict__ ascale)        // [1]
{
  __shared__ float scores[16*2052];          // 16 rows, +4 pad
  __shared__ float row_m[16], row_rl[16];
  const int t = threadIdx.x;
  const int w = t >> 6, l = t & 63;
  const int qt = blockIdx.x, h = blockIdx.y, b = blockIdx.z;
  const int bh = b*NH + h;
  const int q0 = qt*16;
  const float scale_eff = 0.125f * ascale[0] * (1.0f + pc[h] * sinf(phase[b]));
  const int lr = l & 15, lg = l >> 4;

  // Q A-frags (all waves identical; L1-cached)
  const unsigned short* qp = Qh + ((size_t)bh*SS + q0 + lr)*HD + lg*8;
  short8 aq0 = *reinterpret_cast<const short8*>(qp);
  short8 aq1 = *reinterpret_cast<const short8*>(qp + 32);

  // ---- phase A: scores = scale_eff * Q K^T (wave w covers t-blocks w*16..w*16+15)
  #pragma unroll 2
  for (int tb = w*16; tb < w*16 + 16; ++tb){
    const unsigned short* kp = Kh + ((size_t)bh*SS + tb*16 + lr)*HD + lg*8;
    short8 bk0 = *reinterpret_cast<const short8*>(kp);
    short8 bk1 = *reinterpret_cast<const short8*>(kp + 32);
    float4v pacc = {};
    pacc = __builtin_amdgcn_mfma_f32_16x16x32_bf16(aq0, bk0, pacc, 0, 0, 0);
    pacc = __builtin_amdgcn_mfma_f32_16x16x32_bf16(aq1, bk1, pacc, 0, 0, 0);
    #pragma unroll
    for (int r = 0; r < 4; ++r)
      scores[(lg*4 + r)*2052 + tb*16 + lr] = pacc[r] * scale_eff;
  }
  __syncthreads();

  // ---- phase B: per-row max and sum of exp (32 threads per row)
  {
    const int row = t >> 5, sub = t & 31;
    const float* sr = scores + row*2052;
    float m = -1e30f;
    for (int c = sub; c < SS; c += 32) m = fmaxf(m, sr[c]);
    #pragma unroll
    for (int msk = 1; msk < 32; msk <<= 1) m = fmaxf(m, __shfl_xor(m, msk, 64));
    float s = 0.f;
    for (int c = sub; c < SS; c += 32) s += __expf(sr[c] - m);
    #pragma unroll
    for (int msk = 1; msk < 32; msk <<= 1) s += __shfl_xor(s, msk, 64);
    if (sub == 0){ row_m[row] = m; row_rl[row] = 1.0f / s; }
  }
  __syncthreads();

  // ---- phase C: normalize; write f32 weights to global (coalesced) + back to LDS
  {
    float* gw = attnW + ((size_t)bh*SS + q0)*SS;
    for (int idx = t*4; idx < 16*SS; idx += 512*4){
      const int row = idx >> 11, col = idx & 2047;
      float4v v = *reinterpret_cast<const float4v*>(scores + row*2052 + col);
      const float mm = row_m[row], rl = row_rl[row];
      float4v o;
      o.x = __expf(v.x - mm) * rl;
      o.y = __expf(v.y - mm) * rl;
      o.z = __expf(v.z - mm) * rl;
      o.w = __expf(v.w - mm) * rl;
      *reinterpret_cast<float4v*>(scores + row*2052 + col) = o;
      *reinterpret_cast<float4v*>(gw + (size_t)row*SS + col) = o;
    }
  }
  __syncthreads();

  // ---- phase D: O = P V ; wave w -> cols (w&3)*16, k-half (w>>2)
  const int col16 = (w & 3)*16;
  const int kh = w >> 2;
  float4v oacc = {};
  const unsigned short* vp = Vt + ((size_t)bh*HD + col16 + lr)*SS;
  #pragma unroll 2
  for (int ks = kh*32; ks < kh*32 + 32; ++ks){
    const int tt = ks*32 + lg*8;
    short8 bvf = *reinterpret_cast<const short8*>(vp + tt);   // V^T row, contiguous t
    float4v s0 = *reinterpret_cast<const float4v*>(scores + lr*2052 + tt);
    float4v s1 = *reinterpret_cast<const float4v*>(scores + lr*2052 + tt + 4);
    short8 af;
    af[0] = (short)f2bf(s0.x); af[1] = (short)f2bf(s0.y);
    af[2] = (short)f2bf(s0.z); af[3] = (short)f2bf(s0.w);
    af[4] = (short)f2bf(s1.x); af[5] = (short)f2bf(s1.y);
    af[6] = (short)f2bf(s1.z); af[7] = (short)f2bf(s1.w);
    oacc = __builtin_amdgcn_mfma_f32_16x16x32_bf16(af, bvf, oacc, 0, 0, 0);
  }
  __syncthreads();
  if (kh == 1){
    #pragma unroll
    for (int r = 0; r < 4; ++r)
      scores[(w - 4)*256 + (lg*4 + r)*16 + lr] = oacc[r];
  }
  __syncthreads();
  if (kh == 0){
    #pragma unroll
    for (int r = 0; r < 4; ++r){
      float v = oacc[r] + scores[w*256 + (lg*4 + r)*16 + lr];
      const int s_ = q0 + lg*4 + r;
      AO[((size_t)b*SS + s_)*DM + h*HD + col16 + lr] = f2bf(v);
    }
  }
}

extern "C" void kernel_launch(void* const* d_in, const int* in_sizes, int n_in,
                              void* d_out, int out_size, void* d_ws, size_t ws_size,
                              hipStream_t stream){
  const float* q      = (const float*)d_in[0];
  const float* k      = (const float*)d_in[1];
  const float* v      = (const float*)d_in[2];
  const float* phase  = (const float*)d_in[3];
  const float* Wq     = (const float*)d_in[4];
  const float* bq     = (const float*)d_in[5];
  const float* Wk     = (const float*)d_in[6];
  const float* bk     = (const float*)d_in[7];
  const float* Wv     = (const float*)d_in[8];
  const float* bv     = (const float*)d_in[9];
  const float* Wo     = (const float*)d_in[10];
  const float* bo     = (const float*)d_in[11];
  const float* pc     = (const float*)d_in[12];
  const float* ascale = (const float*)d_in[13];
  const float* stab   = (const float*)d_in[14];

  unsigned short* Xq  = (unsigned short*)d_ws;
  unsigned short* Xk  = Xq  + 4194304;
  unsigned short* Xv  = Xk  + 4194304;
  unsigned short* Wqb = Xv  + 4194304;
  unsigned short* Wkb = Wqb + 1048576;
  unsigned short* Wvb = Wkb + 1048576;
  unsigned short* Wob = Wvb + 1048576;
  unsigned short* Qh  = Wob + 1048576;
  unsigned short* Kh  = Qh  + 4194304;
  unsigned short* Vt  = Kh  + 4194304;
  unsigned short* AO  = Vt  + 4194304;   // total 64 MB of ws

  float* out0  = (float*)d_out;
  float* attnW = out0 + (size_t)MTOT*DM;

  cvt_kernel<<<512, 256, 0, stream>>>(q, Xq, MTOT*DM);
  cvt_kernel<<<512, 256, 0, stream>>>(k, Xk, MTOT*DM);
  cvt_kernel<<<512, 256, 0, stream>>>(v, Xv, MTOT*DM);
  cvt_kernel<<<256, 256, 0, stream>>>(Wq, Wqb, DM*DM);
  cvt_kernel<<<256, 256, 0, stream>>>(Wk, Wkb, DM*DM);
  cvt_kernel<<<256, 256, 0, stream>>>(Wv, Wvb, DM*DM);
  cvt_kernel<<<256, 256, 0, stream>>>(Wo, Wob, DM*DM);

  dim3 gg(DM/128, MTOT/128);
  gemm_bt<0><<<gg, 256, 0, stream>>>(Xq, Wqb, bq, Qh, MTOT, DM, DM, nullptr);
  gemm_bt<0><<<gg, 256, 0, stream>>>(Xk, Wkb, bk, Kh, MTOT, DM, DM, nullptr);
  gemm_bt<1><<<gg, 256, 0, stream>>>(Xv, Wvb, bv, Vt, MTOT, DM, DM, nullptr);

  attn_kernel<<<dim3(SS/16, NH, 2), 512, 0, stream>>>(Qh, Kh, Vt, AO, attnW,
                                                      phase, pc, ascale);

  gemm_bt<2><<<gg, 256, 0, stream>>>(AO, Wob, bo, out0, MTOT, DM, DM, stab);
}

// Round 2
// 494.595 us; speedup vs baseline: 1.2347x; 1.2347x over previous
//
#include <hip/hip_runtime.h>
#include <hip/hip_bf16.h>
#include <cstdint>
#include <cstddef>

#define NH 16
#define HD 64
#define SS 2048
#define DM 1024
#define MTOT 4096   // B*S

typedef __attribute__((ext_vector_type(8))) short short8;
typedef __attribute__((ext_vector_type(4))) float float4v;
typedef __attribute__((ext_vector_type(2))) float float2v;
typedef __attribute__((ext_vector_type(4))) unsigned short ushort4v;

__device__ __forceinline__ unsigned short f2bf(float f){
  unsigned int u = __builtin_bit_cast(unsigned int, f);
  u += 0x7FFFu + ((u >> 16) & 1u);   // RNE; inputs finite
  return (unsigned short)(u >> 16);
}

__device__ __forceinline__ void gload16(const void* g, void* l){
  __builtin_amdgcn_global_load_lds((const __attribute__((address_space(1))) void*)g,
                                   (__attribute__((address_space(3))) void*)l, 16, 0, 0);
}

// ---------- f32 -> bf16 bulk convert ----------
__global__ __launch_bounds__(256) void cvt_kernel(const float* __restrict__ src,
                                                  unsigned short* __restrict__ dst, int n){
  for (int i = (blockIdx.x*blockDim.x + threadIdx.x)*4; i < n; i += gridDim.x*blockDim.x*4){
    float4v v = *reinterpret_cast<const float4v*>(src + i);
    ushort4v o;
    o.x = f2bf(v.x); o.y = f2bf(v.y); o.z = f2bf(v.z); o.w = f2bf(v.w);
    *reinterpret_cast<ushort4v*>(dst + i) = o;
  }
}

// ---------- GEMM: out = A[M][K] @ Bw[N][K]^T + bias ----------
// MODE 0: bf16 out, head-split [B,H,S,64]
// MODE 1: bf16 out, V-transposed [B,H,64,S]
// MODE 2: f32 out, row-major, * oscale
template<int MODE>
__global__ __launch_bounds__(256) void gemm_bt(const unsigned short* __restrict__ A,
                                               const unsigned short* __restrict__ Bw,
                                               const float* __restrict__ bias,
                                               void* __restrict__ outp,
                                               int M, int N, int K,
                                               const float* __restrict__ oscale_p){
  __shared__ unsigned short Alds[128*32];
  __shared__ unsigned short Blds[128*32];
  const int t = threadIdx.x;
  const int l = t & 63;
  const int w = t >> 6;
  const int m0 = blockIdx.y * 128, n0 = blockIdx.x * 128;
  const int wm = (w & 1)*64, wn = (w >> 1)*64;
  const int srow = t >> 2;          // staging row
  const int scol = (t & 3)*8;       // staging col (bf16 elems)
  const int lr = l & 15, lg = l >> 4;
  float4v acc[4][4] = {};
  for (int k0 = 0; k0 < K; k0 += 32){
    __syncthreads();                 // prior reads done before overwrite
    gload16(A  + (size_t)(m0 + srow     )*K + k0 + scol, Alds + t*8);
    gload16(A  + (size_t)(m0 + srow + 64)*K + k0 + scol, Alds + 2048 + t*8);
    gload16(Bw + (size_t)(n0 + srow     )*K + k0 + scol, Blds + t*8);
    gload16(Bw + (size_t)(n0 + srow + 64)*K + k0 + scol, Blds + 2048 + t*8);
    asm volatile("s_waitcnt vmcnt(0)" ::: "memory");
    __syncthreads();
    short8 afrag[4], bfrag[4];
    #pragma unroll
    for (int mb = 0; mb < 4; ++mb)
      afrag[mb] = *reinterpret_cast<const short8*>(Alds + (wm + mb*16 + lr)*32 + lg*8);
    #pragma unroll
    for (int nb = 0; nb < 4; ++nb)
      bfrag[nb] = *reinterpret_cast<const short8*>(Blds + (wn + nb*16 + lr)*32 + lg*8);
    #pragma unroll
    for (int mb = 0; mb < 4; ++mb)
      #pragma unroll
      for (int nb = 0; nb < 4; ++nb)
        acc[mb][nb] = __builtin_amdgcn_mfma_f32_16x16x32_bf16(afrag[mb], bfrag[nb], acc[mb][nb], 0, 0, 0);
  }
  const float osc = (MODE == 2) ? oscale_p[0] : 1.0f;
  #pragma unroll
  for (int mb = 0; mb < 4; ++mb){
    #pragma unroll
    for (int nb = 0; nb < 4; ++nb){
      const int gn = n0 + wn + nb*16 + lr;
      const float biasv = bias[gn];
      #pragma unroll
      for (int r = 0; r < 4; ++r){
        const int gm = m0 + wm + mb*16 + lg*4 + r;
        float v = acc[mb][nb][r] + biasv;
        if (MODE == 2){
          reinterpret_cast<float*>(outp)[(size_t)gm*N + gn] = v * osc;
        } else {
          const int b_ = gm >> 11, s_ = gm & 2047, h_ = gn >> 6, d_ = gn & 63;
          unsigned short* o = reinterpret_cast<unsigned short*>(outp);
          if (MODE == 0)
            o[((size_t)(b_*NH + h_)*SS + s_)*HD + d_] = f2bf(v);
          else
            o[((size_t)(b_*NH + h_)*HD + d_)*SS + s_] = f2bf(v);
        }
      }
    }
  }
}

// ---------- fused attention: two-pass flash-style, recompute scores ----------
// Block: 256 threads = 4 waves. 16 q-rows per block. Wave w owns t in
// [w*512,(w+1)*512). Pass 1: online (m,l) in registers. Pass 2: recompute
// scores, normalize, LDS-bounce 16x32 tile -> coalesced f32 attnW store +
// bf16 A-frag for PV MFMA. Cross-wave O reduce at the end.
__global__ __launch_bounds__(256, 4) void attn_kernel(
    const unsigned short* __restrict__ Qh,   // [B*H][S][64] bf16
    const unsigned short* __restrict__ Kh,   // [B*H][S][64] bf16
    const unsigned short* __restrict__ Vt,   // [B*H][64][S] bf16
    unsigned short* __restrict__ AO,         // [B][S][1024] bf16
    float* __restrict__ attnW,               // [B*H][S][S] f32
    const float* __restrict__ phase,         // [B]
    const float* __restrict__ pc,            // [16]
    const float* __restrict__ ascale)        // [1]
{
  __shared__ __attribute__((aligned(16))) float ptile[4][16*34]; // per-wave, stride 34
  __shared__ float mred[4][16], lred[4][16];
  __shared__ __attribute__((aligned(16))) float ored[4][16*64];

  const int t = threadIdx.x;
  const int w = t >> 6, l = t & 63;
  const int lr = l & 15, lg = l >> 4;
  const int qt = blockIdx.x, h = blockIdx.y, b = blockIdx.z;
  const int bh = b*NH + h;
  const int q0 = qt*16;
  const float scale_eff = 0.125f * ascale[0] * (1.0f + pc[h] * sinf(phase[b]));

  // Q A-frags (held in registers for both passes)
  const unsigned short* qp = Qh + ((size_t)bh*SS + q0 + lr)*HD + lg*8;
  const short8 aq0 = *reinterpret_cast<const short8*>(qp);
  const short8 aq1 = *reinterpret_cast<const short8*>(qp + 32);

  const int tbase = w * 512;
  const unsigned short* kbase = Kh + ((size_t)bh*SS + tbase + lr)*HD + lg*8;

  // ---- pass 1: online row max + denom over this wave's 512 t-cols
  float m[4], lsum[4];
  #pragma unroll
  for (int r = 0; r < 4; ++r){ m[r] = -1e30f; lsum[r] = 0.f; }
  #pragma unroll 2
  for (int tb = 0; tb < 32; ++tb){
    const unsigned short* kp = kbase + (size_t)tb*16*HD;
    short8 bk0 = *reinterpret_cast<const short8*>(kp);
    short8 bk1 = *reinterpret_cast<const short8*>(kp + 32);
    float4v pacc = {};
    pacc = __builtin_amdgcn_mfma_f32_16x16x32_bf16(aq0, bk0, pacc, 0, 0, 0);
    pacc = __builtin_amdgcn_mfma_f32_16x16x32_bf16(aq1, bk1, pacc, 0, 0, 0);
    #pragma unroll
    for (int r = 0; r < 4; ++r){
      float s = pacc[r] * scale_eff;
      float nm = fmaxf(m[r], s);
      lsum[r] = lsum[r]*__expf(m[r]-nm) + __expf(s-nm);
      m[r] = nm;
    }
  }
  // reduce (m,l) across the 16 lr-lanes of each lg group
  #pragma unroll
  for (int mask = 1; mask < 16; mask <<= 1){
    #pragma unroll
    for (int r = 0; r < 4; ++r){
      float om = __shfl_xor(m[r], mask, 64);
      float ol = __shfl_xor(lsum[r], mask, 64);
      float nm = fmaxf(m[r], om);
      lsum[r] = lsum[r]*__expf(m[r]-nm) + ol*__expf(om-nm);
      m[r] = nm;
    }
  }
  if (lr == 0){
    #pragma unroll
    for (int r = 0; r < 4; ++r){ mred[w][lg*4+r] = m[r]; lred[w][lg*4+r] = lsum[r]; }
  }
  __syncthreads();
  float rm[4], rrl[4];
  #pragma unroll
  for (int r = 0; r < 4; ++r){
    const int row = lg*4 + r;
    float fm = mred[0][row], fl = lred[0][row];
    #pragma unroll
    for (int ww = 1; ww < 4; ++ww){
      float om = mred[ww][row], ol = lred[ww][row];
      float nm = fmaxf(fm, om);
      fl = fl*__expf(fm-nm) + ol*__expf(om-nm);
      fm = nm;
    }
    rm[r] = fm; rrl[r] = 1.0f/fl;
  }

  // ---- pass 2: recompute scores, normalize, write attnW, accumulate PV
  float4v oacc[4] = {};
  float* ptw = &ptile[w][0];
  const float2v* ptr2 = reinterpret_cast<const float2v*>(ptw);
  float* gw = attnW + ((size_t)bh*SS + q0)*SS + tbase;
  const unsigned short* vbase = Vt + ((size_t)bh*HD + lr)*SS + tbase + lg*8;

  for (int tp = 0; tp < 16; ++tp){
    const int tloc = tp*32;
    #pragma unroll
    for (int hb = 0; hb < 2; ++hb){
      const unsigned short* kp = kbase + (size_t)(tloc + hb*16)*HD;
      short8 bk0 = *reinterpret_cast<const short8*>(kp);
      short8 bk1 = *reinterpret_cast<const short8*>(kp + 32);
      float4v pacc = {};
      pacc = __builtin_amdgcn_mfma_f32_16x16x32_bf16(aq0, bk0, pacc, 0, 0, 0);
      pacc = __builtin_amdgcn_mfma_f32_16x16x32_bf16(aq1, bk1, pacc, 0, 0, 0);
      #pragma unroll
      for (int r = 0; r < 4; ++r){
        float e = __expf(pacc[r]*scale_eff - rm[r]) * rrl[r];
        ptw[(lg*4+r)*34 + hb*16 + lr] = e;     // 2-way bank aliasing: free
      }
    }
    asm volatile("s_waitcnt lgkmcnt(0)" ::: "memory");  // wave-local exchange
    // coalesced attnW store (nontemporal: don't thrash K/V out of L2)
    #pragma unroll
    for (int j = 0; j < 2; ++j){
      const int f = l + 64*j;
      const int row = f >> 3, cg = f & 7;
      float2v a  = ptr2[row*17 + cg*2];
      float2v c2 = ptr2[row*17 + cg*2 + 1];
      float4v ov = {a.x, a.y, c2.x, c2.y};
      __builtin_nontemporal_store(ov, reinterpret_cast<float4v*>(gw + (size_t)row*SS + tloc + cg*4));
    }
    // PV A-frag: P[q=lr][k=lg*8..+7] from the tile, f32 -> bf16
    float2v p0 = ptr2[lr*17 + lg*4 + 0];
    float2v p1 = ptr2[lr*17 + lg*4 + 1];
    float2v p2 = ptr2[lr*17 + lg*4 + 2];
    float2v p3 = ptr2[lr*17 + lg*4 + 3];
    short8 pa;
    pa[0]=(short)f2bf(p0.x); pa[1]=(short)f2bf(p0.y);
    pa[2]=(short)f2bf(p1.x); pa[3]=(short)f2bf(p1.y);
    pa[4]=(short)f2bf(p2.x); pa[5]=(short)f2bf(p2.y);
    pa[6]=(short)f2bf(p3.x); pa[7]=(short)f2bf(p3.y);
    #pragma unroll
    for (int dt = 0; dt < 4; ++dt){
      short8 bv = *reinterpret_cast<const short8*>(vbase + (size_t)(dt*16)*SS + tloc);
      oacc[dt] = __builtin_amdgcn_mfma_f32_16x16x32_bf16(pa, bv, oacc[dt], 0, 0, 0);
    }
  }

  // ---- combine partial O across waves, store AO slice
  #pragma unroll
  for (int dt = 0; dt < 4; ++dt)
    #pragma unroll
    for (int r = 0; r < 4; ++r)
      ored[w][(lg*4+r)*64 + dt*16 + lr] = oacc[dt][r];
  __syncthreads();
  {
    const int q = t >> 4, d = (t & 15)*4;
    const float4v* o0 = reinterpret_cast<const float4v*>(&ored[0][0]);
    const int fi = (q*64 + d) >> 2;
    float4v s = o0[fi];
    s += o0[fi + 256];
    s += o0[fi + 512];
    s += o0[fi + 768];
    ushort4v o4;
    o4.x = f2bf(s.x); o4.y = f2bf(s.y); o4.z = f2bf(s.z); o4.w = f2bf(s.w);
    *reinterpret_cast<ushort4v*>(AO + ((size_t)b*SS + q0 + q)*DM + h*HD + d) = o4;
  }
}

extern "C" void kernel_launch(void* const* d_in, const int* in_sizes, int n_in,
                              void* d_out, int out_size, void* d_ws, size_t ws_size,
                              hipStream_t stream){
  const float* q      = (const float*)d_in[0];
  const float* k      = (const float*)d_in[1];
  const float* v      = (const float*)d_in[2];
  const float* phase  = (const float*)d_in[3];
  const float* Wq     = (const float*)d_in[4];
  const float* bq     = (const float*)d_in[5];
  const float* Wk     = (const float*)d_in[6];
  const float* bk     = (const float*)d_in[7];
  const float* Wv     = (const float*)d_in[8];
  const float* bv     = (const float*)d_in[9];
  const float* Wo     = (const float*)d_in[10];
  const float* bo     = (const float*)d_in[11];
  const float* pc     = (const float*)d_in[12];
  const float* ascale = (const float*)d_in[13];
  const float* stab   = (const float*)d_in[14];

  unsigned short* Xq  = (unsigned short*)d_ws;
  unsigned short* Xk  = Xq  + 4194304;
  unsigned short* Xv  = Xk  + 4194304;
  unsigned short* Wqb = Xv  + 4194304;
  unsigned short* Wkb = Wqb + 1048576;
  unsigned short* Wvb = Wkb + 1048576;
  unsigned short* Wob = Wvb + 1048576;
  unsigned short* Qh  = Wob + 1048576;
  unsigned short* Kh  = Qh  + 4194304;
  unsigned short* Vt  = Kh  + 4194304;
  unsigned short* AO  = Vt  + 4194304;   // total 64 MB of ws

  float* out0  = (float*)d_out;
  float* attnW = out0 + (size_t)MTOT*DM;

  cvt_kernel<<<512, 256, 0, stream>>>(q, Xq, MTOT*DM);
  cvt_kernel<<<512, 256, 0, stream>>>(k, Xk, MTOT*DM);
  cvt_kernel<<<512, 256, 0, stream>>>(v, Xv, MTOT*DM);
  cvt_kernel<<<256, 256, 0, stream>>>(Wq, Wqb, DM*DM);
  cvt_kernel<<<256, 256, 0, stream>>>(Wk, Wkb, DM*DM);
  cvt_kernel<<<256, 256, 0, stream>>>(Wv, Wvb, DM*DM);
  cvt_kernel<<<256, 256, 0, stream>>>(Wo, Wob, DM*DM);

  dim3 gg(DM/128, MTOT/128);
  gemm_bt<0><<<gg, 256, 0, stream>>>(Xq, Wqb, bq, Qh, MTOT, DM, DM, nullptr);
  gemm_bt<0><<<gg, 256, 0, stream>>>(Xk, Wkb, bk, Kh, MTOT, DM, DM, nullptr);
  gemm_bt<1><<<gg, 256, 0, stream>>>(Xv, Wvb, bv, Vt, MTOT, DM, DM, nullptr);

  attn_kernel<<<dim3(SS/16, NH, 2), 256, 0, stream>>>(Qh, Kh, Vt, AO, attnW,
                                                      phase, pc, ascale);

  gemm_bt<2><<<gg, 256, 0, stream>>>(AO, Wob, bo, out0, MTOT, DM, DM, stab);
}